// Round 1
// baseline (459.405 us; speedup 1.0000x reference)
//
#include <hip/hip_runtime.h>
#include <hip/hip_bf16.h>

#define D 128
#define CAP 64   // max in-degree slots per node (Poisson(12); P(>=64) ~ 1e-24)

// ---------------------------------------------------------------------------
// Build padded adjacency (pull lists) + weighted in-degree denominators.
// ---------------------------------------------------------------------------
__global__ __launch_bounds__(256) void fill_edges(
    const int* __restrict__ ei, const float* __restrict__ w,
    int* __restrict__ cnt, float* __restrict__ denom,
    int* __restrict__ pad_src, float* __restrict__ pad_w, int E)
{
    int e = blockIdx.x * 256 + threadIdx.x;
    if (e >= E) return;
    int s = ei[e];
    int d = ei[E + e];
    float wv = w[e];
    int pos = atomicAdd(&cnt[d], 1);
    if (pos < CAP) {
        pad_src[(size_t)d * CAP + pos] = s;
        pad_w[(size_t)d * CAP + pos]   = wv;
    }
    atomicAdd(&denom[d], wv);
}

// ---------------------------------------------------------------------------
// Pull-style weighted-mean aggregation: 2 nodes per 256-thread block,
// one lane per feature column. Row gathers are coalesced 512B reads.
// ---------------------------------------------------------------------------
__global__ __launch_bounds__(256) void aggregate(
    const float* __restrict__ x, const int* __restrict__ cnt,
    const float* __restrict__ denom, const int* __restrict__ pad_src,
    const float* __restrict__ pad_w, float* __restrict__ agg, int N)
{
    int n = blockIdx.x * 2 + (threadIdx.x >> 7);
    int d = threadIdx.x & 127;
    if (n >= N) return;
    int deg = cnt[n];
    if (deg > CAP) deg = CAP;
    size_t base = (size_t)n * CAP;
    float acc = 0.f;
    for (int j = 0; j < deg; ++j) {
        int s    = pad_src[base + j];
        float wv = pad_w[base + j];
        acc += wv * x[(size_t)s * D + d];
    }
    float dn = fmaxf(denom[n], 1e-12f);
    agg[(size_t)n * D + d] = acc / dn;
}

// ---------------------------------------------------------------------------
// Fused GEMM: xout = relu(xin @ Ws + agg @ Wn + bias)
// Treated as A=[xin|agg] (K=256) @ B=[Ws;Wn] (256x128).
// BM=64 rows/block, BK=64 k-chunk, 256 threads, 8x4 micro-tile/thread.
// A staged transposed in LDS (broadcast reads), B staged row-major.
// In-place (xout==xin) is safe: each block reads only its own A-rows.
// ---------------------------------------------------------------------------
#define BM 64
#define BK 64

__global__ __launch_bounds__(256) void gemm_fused(
    const float* __restrict__ xin, const float* __restrict__ agg,
    const float* __restrict__ Ws, const float* __restrict__ Wn,
    const float* __restrict__ bias, float* __restrict__ xout, int nrows)
{
    __shared__ float At[BK][BM + 4];   // stride 68 floats = 272B (16B aligned)
    __shared__ float Bs[BK][D];
    const int tid  = threadIdx.x;
    const int row0 = blockIdx.x * BM;
    const int rg   = tid >> 5;   // 0..7  -> rows rg*8..rg*8+7
    const int cg   = tid & 31;   // 0..31 -> cols cg*4..cg*4+3

    float acc[8][4];
    #pragma unroll
    for (int i = 0; i < 8; ++i)
        #pragma unroll
        for (int j = 0; j < 4; ++j) acc[i][j] = 0.f;

    const int ar  = tid >> 2;         // 0..63 staging row
    const int akq = (tid & 3) * 16;   // k quarter within chunk

    for (int kc = 0; kc < 4; ++kc) {
        // ---- stage A chunk (transposed) ----
        {
            const float* src = (kc < 2) ? xin : agg;
            const int kb = (kc & 1) * 64;
            const int grow = row0 + ar;
            if (grow < nrows) {
                const float4* p = (const float4*)(src + (size_t)grow * D + kb + akq);
                #pragma unroll
                for (int v = 0; v < 4; ++v) {
                    float4 f = p[v];
                    At[akq + v * 4 + 0][ar] = f.x;
                    At[akq + v * 4 + 1][ar] = f.y;
                    At[akq + v * 4 + 2][ar] = f.z;
                    At[akq + v * 4 + 3][ar] = f.w;
                }
            } else {
                #pragma unroll
                for (int v = 0; v < 16; ++v) At[akq + v][ar] = 0.f;
            }
        }
        // ---- stage B chunk ----
        {
            const int gk = kc * 64 + ar;   // 0..255 stacked row
            const float* brow = (gk < D) ? (Ws + (size_t)gk * D)
                                         : (Wn + (size_t)(gk - D) * D);
            const int seg = (tid & 3) * 32;
            float4* dp = (float4*)(&Bs[ar][seg]);
            const float4* sp = (const float4*)(brow + seg);
            #pragma unroll
            for (int v = 0; v < 8; ++v) dp[v] = sp[v];
        }
        __syncthreads();
        // ---- compute ----
        #pragma unroll 8
        for (int k = 0; k < BK; ++k) {
            float4 a0 = *(const float4*)&At[k][rg * 8];
            float4 a1 = *(const float4*)&At[k][rg * 8 + 4];
            float4 b  = *(const float4*)&Bs[k][cg * 4];
            float a[8] = {a0.x, a0.y, a0.z, a0.w, a1.x, a1.y, a1.z, a1.w};
            float bb[4] = {b.x, b.y, b.z, b.w};
            #pragma unroll
            for (int i = 0; i < 8; ++i)
                #pragma unroll
                for (int j = 0; j < 4; ++j)
                    acc[i][j] += a[i] * bb[j];
        }
        __syncthreads();
    }
    // ---- epilogue: bias + relu + store ----
    float4 bv = *(const float4*)&bias[cg * 4];
    #pragma unroll
    for (int i = 0; i < 8; ++i) {
        int grow = row0 + rg * 8 + i;
        if (grow < nrows) {
            float4 o;
            o.x = fmaxf(acc[i][0] + bv.x, 0.f);
            o.y = fmaxf(acc[i][1] + bv.y, 0.f);
            o.z = fmaxf(acc[i][2] + bv.z, 0.f);
            o.w = fmaxf(acc[i][3] + bv.w, 0.f);
            *(float4*)(xout + (size_t)grow * D + cg * 4) = o;
        }
    }
}

// ---------------------------------------------------------------------------
// out[q] = x2[x_nodes[q]] + effect_emb[effect_ids[q]]   (float4 per thread)
// ---------------------------------------------------------------------------
__global__ __launch_bounds__(256) void out_kernel(
    const float* __restrict__ x, const float* __restrict__ emb,
    const int* __restrict__ xn, const int* __restrict__ eid,
    float* __restrict__ out, int Q)
{
    long g = (long)blockIdx.x * 256 + threadIdx.x;   // float4 index
    long tot = (long)Q * (D / 4);
    if (g >= tot) return;
    int q = (int)(g >> 5);
    int c = (int)(g & 31);
    int nq = xn[q], ef = eid[q];
    const float4* xr = (const float4*)(x + (size_t)nq * D);
    const float4* er = (const float4*)(emb + (size_t)ef * D);
    float4 a = xr[c], b = er[c];
    float4 o = {a.x + b.x, a.y + b.y, a.z + b.z, a.w + b.w};
    ((float4*)out)[g] = o;
}

extern "C" void kernel_launch(void* const* d_in, const int* in_sizes, int n_in,
                              void* d_out, int out_size, void* d_ws, size_t ws_size,
                              hipStream_t stream)
{
    const float* graph_x   = (const float*)d_in[0];
    const int*   edge_idx  = (const int*)d_in[1];
    const int*   x_nodes   = (const int*)d_in[2];
    const int*   effect_id = (const int*)d_in[3];
    const float* chem      = (const float*)d_in[4];
    const float* W_self    = (const float*)d_in[5];
    const float* W_neigh   = (const float*)d_in[6];
    const float* bias      = (const float*)d_in[7];
    const float* eff_emb   = (const float*)d_in[8];

    const int N = in_sizes[0] / D;
    const int E = in_sizes[4];
    const int Q = in_sizes[2];

    // workspace carve (all offsets 16B aligned)
    char* wsp = (char*)d_ws;
    int*   cnt     = (int*)wsp;                 wsp += (size_t)N * 4;
    float* denom   = (float*)wsp;               wsp += (size_t)N * 4;
    int*   pad_src = (int*)wsp;                 wsp += (size_t)N * CAP * 4;
    float* pad_w   = (float*)wsp;               wsp += (size_t)N * CAP * 4;
    float* agg     = (float*)wsp;               wsp += (size_t)N * D * 4;
    float* x1      = (float*)wsp;               wsp += (size_t)N * D * 4;

    // zero cnt + denom (adjacent regions)
    hipMemsetAsync(cnt, 0, (size_t)N * 8, stream);

    fill_edges<<<(E + 255) / 256, 256, 0, stream>>>(
        edge_idx, chem, cnt, denom, pad_src, pad_w, E);

    const int aggGrid  = (N + 1) / 2;
    const int gemmGrid = (N + BM - 1) / BM;

    // hop 1
    aggregate<<<aggGrid, 256, 0, stream>>>(graph_x, cnt, denom, pad_src, pad_w, agg, N);
    gemm_fused<<<gemmGrid, 256, 0, stream>>>(
        graph_x, agg, W_self, W_neigh, bias, x1, N);

    // hop 2 (in-place x1 update is safe: blocks own disjoint row ranges)
    aggregate<<<aggGrid, 256, 0, stream>>>(x1, cnt, denom, pad_src, pad_w, agg, N);
    gemm_fused<<<gemmGrid, 256, 0, stream>>>(
        x1, agg, W_self + D * D, W_neigh + D * D, bias + D, x1, N);

    // final gather + effect embedding add
    long tot4 = (long)Q * (D / 4);
    out_kernel<<<(int)((tot4 + 255) / 256), 256, 0, stream>>>(
        x1, eff_emb, x_nodes, effect_id, (float*)d_out, Q);
}

// Round 2
// 319.416 us; speedup vs baseline: 1.4383x; 1.4383x over previous
//
#include <hip/hip_runtime.h>
#include <hip/hip_bf16.h>

#define D 128
#define CAP 64   // max in-degree slots per node (Poisson(12); P(>=64) ~ 1e-24)

// ---------------------------------------------------------------------------
// Build padded adjacency (pull lists) + weighted in-degree denominators.
// ---------------------------------------------------------------------------
__global__ __launch_bounds__(256) void fill_edges(
    const int* __restrict__ ei, const float* __restrict__ w,
    int* __restrict__ cnt, float* __restrict__ denom,
    int* __restrict__ pad_src, float* __restrict__ pad_w, int E)
{
    int e = blockIdx.x * 256 + threadIdx.x;
    if (e >= E) return;
    int s = ei[e];
    int d = ei[E + e];
    float wv = w[e];
    int pos = atomicAdd(&cnt[d], 1);
    if (pos < CAP) {
        pad_src[(size_t)d * CAP + pos] = s;
        pad_w[(size_t)d * CAP + pos]   = wv;
    }
    atomicAdd(&denom[d], wv);
}

// ---------------------------------------------------------------------------
// Pull-style weighted-mean aggregation, latency-optimized:
// one node per 64-lane wave (4 nodes / 256-thread block).
//   lane = jj*32 + c : c = float4 column group (32 x 4 = 128 cols)
//                      jj = j-slice (2 slices)
// Per step: int4/float4 vector load of 4 adjacency slots, then 4 independent
// row gathers -> 8 gathers in flight per node (2 slices x 4 unroll) instead
// of 1. Cross-slice reduce via __shfl_xor(32).
// Slots >= deg hold poison garbage -> predicate index/weight to (0, 0.f)
// before address use (row 0 is always a valid address).
// ---------------------------------------------------------------------------
__global__ __launch_bounds__(256) void aggregate(
    const float* __restrict__ x, const int* __restrict__ cnt,
    const float* __restrict__ denom, const int* __restrict__ pad_src,
    const float* __restrict__ pad_w, float* __restrict__ agg, int N)
{
    const int wave = threadIdx.x >> 6;
    const int lane = threadIdx.x & 63;
    const int n = blockIdx.x * 4 + wave;
    if (n >= N) return;
    const int c  = lane & 31;
    const int jj = lane >> 5;

    int deg = cnt[n];
    if (deg > CAP) deg = CAP;
    const size_t base = (size_t)n * CAP;

    float4 acc = {0.f, 0.f, 0.f, 0.f};

    for (int t = 0; t < deg; t += 8) {
        const int j = t + jj * 4;
        // vector load 4 adjacency slots (16B aligned: base%16==0, j%4==0)
        int4   s4 = *(const int4*)  (pad_src + base + j);
        float4 w4 = *(const float4*)(pad_w   + base + j);
        // predicate poison slots
        const int s0 = (j + 0 < deg) ? s4.x : 0;
        const int s1 = (j + 1 < deg) ? s4.y : 0;
        const int s2 = (j + 2 < deg) ? s4.z : 0;
        const int s3 = (j + 3 < deg) ? s4.w : 0;
        const float w0 = (j + 0 < deg) ? w4.x : 0.f;
        const float w1 = (j + 1 < deg) ? w4.y : 0.f;
        const float w2 = (j + 2 < deg) ? w4.z : 0.f;
        const float w3 = (j + 3 < deg) ? w4.w : 0.f;
        // 4 independent row gathers (each wave-wide instr covers 2 rows)
        float4 v0 = *((const float4*)(x + (size_t)s0 * D) + c);
        float4 v1 = *((const float4*)(x + (size_t)s1 * D) + c);
        float4 v2 = *((const float4*)(x + (size_t)s2 * D) + c);
        float4 v3 = *((const float4*)(x + (size_t)s3 * D) + c);
        acc.x += w0 * v0.x + w1 * v1.x + w2 * v2.x + w3 * v3.x;
        acc.y += w0 * v0.y + w1 * v1.y + w2 * v2.y + w3 * v3.y;
        acc.z += w0 * v0.z + w1 * v1.z + w2 * v2.z + w3 * v3.z;
        acc.w += w0 * v0.w + w1 * v1.w + w2 * v2.w + w3 * v3.w;
    }

    // reduce the two j-slices (lane ^ 32)
    acc.x += __shfl_xor(acc.x, 32, 64);
    acc.y += __shfl_xor(acc.y, 32, 64);
    acc.z += __shfl_xor(acc.z, 32, 64);
    acc.w += __shfl_xor(acc.w, 32, 64);

    if (jj == 0) {
        const float inv = 1.f / fmaxf(denom[n], 1e-12f);
        float4 o = {acc.x * inv, acc.y * inv, acc.z * inv, acc.w * inv};
        *((float4*)(agg + (size_t)n * D) + c) = o;
    }
}

// ---------------------------------------------------------------------------
// Fused GEMM: xout = relu(xin @ Ws + agg @ Wn + bias)
// Treated as A=[xin|agg] (K=256) @ B=[Ws;Wn] (256x128).
// BM=64 rows/block, BK=64 k-chunk, 256 threads, 8x4 micro-tile/thread.
// ---------------------------------------------------------------------------
#define BM 64
#define BK 64

__global__ __launch_bounds__(256) void gemm_fused(
    const float* __restrict__ xin, const float* __restrict__ agg,
    const float* __restrict__ Ws, const float* __restrict__ Wn,
    const float* __restrict__ bias, float* __restrict__ xout, int nrows)
{
    __shared__ float At[BK][BM + 4];
    __shared__ float Bs[BK][D];
    const int tid  = threadIdx.x;
    const int row0 = blockIdx.x * BM;
    const int rg   = tid >> 5;
    const int cg   = tid & 31;

    float acc[8][4];
    #pragma unroll
    for (int i = 0; i < 8; ++i)
        #pragma unroll
        for (int j = 0; j < 4; ++j) acc[i][j] = 0.f;

    const int ar  = tid >> 2;
    const int akq = (tid & 3) * 16;

    for (int kc = 0; kc < 4; ++kc) {
        {
            const float* src = (kc < 2) ? xin : agg;
            const int kb = (kc & 1) * 64;
            const int grow = row0 + ar;
            if (grow < nrows) {
                const float4* p = (const float4*)(src + (size_t)grow * D + kb + akq);
                #pragma unroll
                for (int v = 0; v < 4; ++v) {
                    float4 f = p[v];
                    At[akq + v * 4 + 0][ar] = f.x;
                    At[akq + v * 4 + 1][ar] = f.y;
                    At[akq + v * 4 + 2][ar] = f.z;
                    At[akq + v * 4 + 3][ar] = f.w;
                }
            } else {
                #pragma unroll
                for (int v = 0; v < 16; ++v) At[akq + v][ar] = 0.f;
            }
        }
        {
            const int gk = kc * 64 + ar;
            const float* brow = (gk < D) ? (Ws + (size_t)gk * D)
                                         : (Wn + (size_t)(gk - D) * D);
            const int seg = (tid & 3) * 32;
            float4* dp = (float4*)(&Bs[ar][seg]);
            const float4* sp = (const float4*)(brow + seg);
            #pragma unroll
            for (int v = 0; v < 8; ++v) dp[v] = sp[v];
        }
        __syncthreads();
        #pragma unroll 8
        for (int k = 0; k < BK; ++k) {
            float4 a0 = *(const float4*)&At[k][rg * 8];
            float4 a1 = *(const float4*)&At[k][rg * 8 + 4];
            float4 b  = *(const float4*)&Bs[k][cg * 4];
            float a[8] = {a0.x, a0.y, a0.z, a0.w, a1.x, a1.y, a1.z, a1.w};
            float bb[4] = {b.x, b.y, b.z, b.w};
            #pragma unroll
            for (int i = 0; i < 8; ++i)
                #pragma unroll
                for (int j = 0; j < 4; ++j)
                    acc[i][j] += a[i] * bb[j];
        }
        __syncthreads();
    }
    float4 bv = *(const float4*)&bias[cg * 4];
    #pragma unroll
    for (int i = 0; i < 8; ++i) {
        int grow = row0 + rg * 8 + i;
        if (grow < nrows) {
            float4 o;
            o.x = fmaxf(acc[i][0] + bv.x, 0.f);
            o.y = fmaxf(acc[i][1] + bv.y, 0.f);
            o.z = fmaxf(acc[i][2] + bv.z, 0.f);
            o.w = fmaxf(acc[i][3] + bv.w, 0.f);
            *(float4*)(xout + (size_t)grow * D + cg * 4) = o;
        }
    }
}

// ---------------------------------------------------------------------------
// out[q] = x2[x_nodes[q]] + effect_emb[effect_ids[q]]   (float4 per thread)
// ---------------------------------------------------------------------------
__global__ __launch_bounds__(256) void out_kernel(
    const float* __restrict__ x, const float* __restrict__ emb,
    const int* __restrict__ xn, const int* __restrict__ eid,
    float* __restrict__ out, int Q)
{
    long g = (long)blockIdx.x * 256 + threadIdx.x;
    long tot = (long)Q * (D / 4);
    if (g >= tot) return;
    int q = (int)(g >> 5);
    int c = (int)(g & 31);
    int nq = xn[q], ef = eid[q];
    const float4* xr = (const float4*)(x + (size_t)nq * D);
    const float4* er = (const float4*)(emb + (size_t)ef * D);
    float4 a = xr[c], b = er[c];
    float4 o = {a.x + b.x, a.y + b.y, a.z + b.z, a.w + b.w};
    ((float4*)out)[g] = o;
}

extern "C" void kernel_launch(void* const* d_in, const int* in_sizes, int n_in,
                              void* d_out, int out_size, void* d_ws, size_t ws_size,
                              hipStream_t stream)
{
    const float* graph_x   = (const float*)d_in[0];
    const int*   edge_idx  = (const int*)d_in[1];
    const int*   x_nodes   = (const int*)d_in[2];
    const int*   effect_id = (const int*)d_in[3];
    const float* chem      = (const float*)d_in[4];
    const float* W_self    = (const float*)d_in[5];
    const float* W_neigh   = (const float*)d_in[6];
    const float* bias      = (const float*)d_in[7];
    const float* eff_emb   = (const float*)d_in[8];

    const int N = in_sizes[0] / D;
    const int E = in_sizes[4];
    const int Q = in_sizes[2];

    char* wsp = (char*)d_ws;
    int*   cnt     = (int*)wsp;                 wsp += (size_t)N * 4;
    float* denom   = (float*)wsp;               wsp += (size_t)N * 4;
    int*   pad_src = (int*)wsp;                 wsp += (size_t)N * CAP * 4;
    float* pad_w   = (float*)wsp;               wsp += (size_t)N * CAP * 4;
    float* agg     = (float*)wsp;               wsp += (size_t)N * D * 4;
    float* x1      = (float*)wsp;               wsp += (size_t)N * D * 4;

    hipMemsetAsync(cnt, 0, (size_t)N * 8, stream);

    fill_edges<<<(E + 255) / 256, 256, 0, stream>>>(
        edge_idx, chem, cnt, denom, pad_src, pad_w, E);

    const int aggGrid  = (N + 3) / 4;
    const int gemmGrid = (N + BM - 1) / BM;

    // hop 1
    aggregate<<<aggGrid, 256, 0, stream>>>(graph_x, cnt, denom, pad_src, pad_w, agg, N);
    gemm_fused<<<gemmGrid, 256, 0, stream>>>(
        graph_x, agg, W_self, W_neigh, bias, x1, N);

    // hop 2
    aggregate<<<aggGrid, 256, 0, stream>>>(x1, cnt, denom, pad_src, pad_w, agg, N);
    gemm_fused<<<gemmGrid, 256, 0, stream>>>(
        x1, agg, W_self + D * D, W_neigh + D * D, bias + D, x1, N);

    // final gather + effect embedding add
    long tot4 = (long)Q * (D / 4);
    out_kernel<<<(int)((tot4 + 255) / 256), 256, 0, stream>>>(
        x1, eff_emb, x_nodes, effect_id, (float*)d_out, Q);
}

// Round 4
// 186.465 us; speedup vs baseline: 2.4638x; 1.7130x over previous
//
#include <hip/hip_runtime.h>
#include <hip/hip_bf16.h>

#define D 128
#define CAP 64   // max in-degree slots per node (Poisson(12); P(>=64) ~ 1e-24)
#define BM 64

using bf16x8 = __attribute__((ext_vector_type(8))) short;
using f32x4  = __attribute__((ext_vector_type(4))) float;

static __device__ __forceinline__ unsigned short f2bf(float f) {
    unsigned u = __float_as_uint(f);
    u += 0x7FFF + ((u >> 16) & 1);          // round-to-nearest-even
    return (unsigned short)(u >> 16);
}
static __device__ __forceinline__ float bf2f(unsigned short s) {
    return __uint_as_float(((unsigned)s) << 16);
}

// ---------------------------------------------------------------------------
// graph_x fp32 -> bf16 (8 elems / thread)
// ---------------------------------------------------------------------------
__global__ __launch_bounds__(256) void convert_x(
    const float* __restrict__ in, ushort* __restrict__ out, long n8)
{
    long i = (long)blockIdx.x * 256 + threadIdx.x;
    if (i >= n8) return;
    const float4* p = (const float4*)in + i * 2;
    float4 a = p[0], b = p[1];
    uint4 o;
    o.x = (unsigned)f2bf(a.x) | ((unsigned)f2bf(a.y) << 16);
    o.y = (unsigned)f2bf(a.z) | ((unsigned)f2bf(a.w) << 16);
    o.z = (unsigned)f2bf(b.x) | ((unsigned)f2bf(b.y) << 16);
    o.w = (unsigned)f2bf(b.z) | ((unsigned)f2bf(b.w) << 16);
    ((uint4*)out)[i] = o;
}

// ---------------------------------------------------------------------------
// Build Wt[h][n][k] (bf16): transposed stack of [W_self ; W_neigh] per hop.
// ---------------------------------------------------------------------------
__global__ __launch_bounds__(256) void prep_wt(
    const float* __restrict__ Ws, const float* __restrict__ Wn,
    ushort* __restrict__ Wt, int total)
{
    int idx = blockIdx.x * 256 + threadIdx.x;
    if (idx >= total) return;
    int h   = idx >> 15;          // /(D*256)
    int rem = idx & 32767;
    int n   = rem >> 8;
    int k   = rem & 255;
    float v = (k < D) ? Ws[(size_t)h * D * D + (size_t)k * D + n]
                      : Wn[(size_t)h * D * D + (size_t)(k - D) * D + n];
    Wt[idx] = f2bf(v);
}

// ---------------------------------------------------------------------------
// Padded adjacency + weighted in-degree denominators.
// ---------------------------------------------------------------------------
__global__ __launch_bounds__(256) void fill_edges(
    const int* __restrict__ ei, const float* __restrict__ w,
    int* __restrict__ cnt, float* __restrict__ denom,
    int* __restrict__ pad_src, float* __restrict__ pad_w, int E)
{
    int e = blockIdx.x * 256 + threadIdx.x;
    if (e >= E) return;
    int s = ei[e];
    int d = ei[E + e];
    float wv = w[e];
    int pos = atomicAdd(&cnt[d], 1);
    if (pos < CAP) {
        pad_src[(size_t)d * CAP + pos] = s;
        pad_w[(size_t)d * CAP + pos]   = wv;
    }
    atomicAdd(&denom[d], wv);
}

// ---------------------------------------------------------------------------
// Weighted-mean aggregation, bf16 features: one node per wave,
// lane = jj*32 + c (c = 4-col group, jj = j-slice), 8 gathers in flight.
// ---------------------------------------------------------------------------
__global__ __launch_bounds__(256) void aggregate(
    const ushort* __restrict__ x, const int* __restrict__ cnt,
    const float* __restrict__ denom, const int* __restrict__ pad_src,
    const float* __restrict__ pad_w, ushort* __restrict__ agg, int N)
{
    const int wave = threadIdx.x >> 6;
    const int lane = threadIdx.x & 63;
    const int n = blockIdx.x * 4 + wave;
    if (n >= N) return;
    const int c  = lane & 31;
    const int jj = lane >> 5;

    int deg = cnt[n];
    if (deg > CAP) deg = CAP;
    const size_t base = (size_t)n * CAP;

    float ax = 0.f, ay = 0.f, az = 0.f, aw = 0.f;

    for (int t = 0; t < deg; t += 8) {
        const int j = t + jj * 4;
        int4   s4 = *(const int4*)  (pad_src + base + j);
        float4 w4 = *(const float4*)(pad_w   + base + j);
        const int s0 = (j + 0 < deg) ? s4.x : 0;
        const int s1 = (j + 1 < deg) ? s4.y : 0;
        const int s2 = (j + 2 < deg) ? s4.z : 0;
        const int s3 = (j + 3 < deg) ? s4.w : 0;
        const float w0 = (j + 0 < deg) ? w4.x : 0.f;
        const float w1 = (j + 1 < deg) ? w4.y : 0.f;
        const float w2 = (j + 2 < deg) ? w4.z : 0.f;
        const float w3 = (j + 3 < deg) ? w4.w : 0.f;
        ushort4 v0 = *((const ushort4*)(x + (size_t)s0 * D) + c);
        ushort4 v1 = *((const ushort4*)(x + (size_t)s1 * D) + c);
        ushort4 v2 = *((const ushort4*)(x + (size_t)s2 * D) + c);
        ushort4 v3 = *((const ushort4*)(x + (size_t)s3 * D) + c);
        ax += w0 * bf2f(v0.x) + w1 * bf2f(v1.x) + w2 * bf2f(v2.x) + w3 * bf2f(v3.x);
        ay += w0 * bf2f(v0.y) + w1 * bf2f(v1.y) + w2 * bf2f(v2.y) + w3 * bf2f(v3.y);
        az += w0 * bf2f(v0.z) + w1 * bf2f(v1.z) + w2 * bf2f(v2.z) + w3 * bf2f(v3.z);
        aw += w0 * bf2f(v0.w) + w1 * bf2f(v1.w) + w2 * bf2f(v2.w) + w3 * bf2f(v3.w);
    }

    ax += __shfl_xor(ax, 32, 64);
    ay += __shfl_xor(ay, 32, 64);
    az += __shfl_xor(az, 32, 64);
    aw += __shfl_xor(aw, 32, 64);

    if (jj == 0) {
        const float inv = 1.f / fmaxf(denom[n], 1e-12f);
        ushort4 o;
        o.x = f2bf(ax * inv); o.y = f2bf(ay * inv);
        o.z = f2bf(az * inv); o.w = f2bf(aw * inv);
        *((ushort4*)(agg + (size_t)n * D) + c) = o;
    }
}

// ---------------------------------------------------------------------------
// MFMA GEMM: xout = relu([xin|agg] @ Wt^T + bias), all bf16 I/O, fp32 acc.
// BM=64 rows/block, 4 waves (wave w = rows w*16..w*16+15), N=128 cols/wave,
// K=256 in 4 chunks of 64. LDS rows padded to 72 bf16.
// A-frag: lane holds A[l&15][8*(l>>4)+e]; B-frag (from transposed Wt):
// lane holds B[8*(l>>4)+e][l&15]; C/D: row=(l>>4)*4+i, col=l&15 (m89).
// ---------------------------------------------------------------------------
__global__ __launch_bounds__(256) void gemm_mfma(
    const ushort* __restrict__ xin, const ushort* __restrict__ agg,
    const ushort* __restrict__ Wt, const float* __restrict__ bias,
    ushort* __restrict__ xout, int nrows)
{
    __shared__ ushort As[BM][72];
    __shared__ ushort Bs[D][72];
    const int tid  = threadIdx.x;
    const int w    = tid >> 6;
    const int lane = tid & 63;
    const int r16  = lane & 15;
    const int kq   = lane >> 4;
    const int row0 = blockIdx.x * BM;

    f32x4 acc[8];
    #pragma unroll
    for (int nf = 0; nf < 8; ++nf) acc[nf] = {0.f, 0.f, 0.f, 0.f};

    for (int kc = 0; kc < 4; ++kc) {
        // stage A chunk: 64 rows x 64 bf16 (4 threads/row x 16 ushorts)
        {
            const ushort* src = (kc < 2) ? xin : agg;
            const int kb = (kc & 1) * 64;
            const int r = tid >> 2, q = tid & 3;
            const int grow = row0 + r;
            if (grow < nrows) {
                const uint4* gp = (const uint4*)(src + (size_t)grow * D + kb + q * 16);
                uint4 v0 = gp[0], v1 = gp[1];
                *(uint4*)&As[r][q * 16]     = v0;
                *(uint4*)&As[r][q * 16 + 8] = v1;
            } else {
                uint4 z = {0u, 0u, 0u, 0u};
                *(uint4*)&As[r][q * 16]     = z;
                *(uint4*)&As[r][q * 16 + 8] = z;
            }
        }
        // stage B chunk: 128 rows x 64 bf16 (2 threads/row x 32 ushorts = 4 uint4)
        {
            const int n = tid >> 1, h2 = tid & 1;
            const uint4* gp = (const uint4*)(Wt + (size_t)n * 256 + kc * 64 + h2 * 32);
            uint4 v0 = gp[0], v1 = gp[1], v2 = gp[2], v3 = gp[3];
            *(uint4*)&Bs[n][h2 * 32]      = v0;
            *(uint4*)&Bs[n][h2 * 32 + 8]  = v1;
            *(uint4*)&Bs[n][h2 * 32 + 16] = v2;
            *(uint4*)&Bs[n][h2 * 32 + 24] = v3;
        }
        __syncthreads();
        #pragma unroll
        for (int kk = 0; kk < 64; kk += 32) {
            bf16x8 a = *(const bf16x8*)&As[w * 16 + r16][kk + kq * 8];
            #pragma unroll
            for (int nf = 0; nf < 8; ++nf) {
                bf16x8 b = *(const bf16x8*)&Bs[nf * 16 + r16][kk + kq * 8];
                acc[nf] = __builtin_amdgcn_mfma_f32_16x16x32_bf16(a, b, acc[nf], 0, 0, 0);
            }
        }
        __syncthreads();
    }
    // epilogue: bias + relu + bf16 store
    #pragma unroll
    for (int nf = 0; nf < 8; ++nf) {
        const int col = nf * 16 + r16;
        const float bv = bias[col];
        #pragma unroll
        for (int i = 0; i < 4; ++i) {
            const int grow = row0 + w * 16 + kq * 4 + i;
            if (grow < nrows) {
                float v = fmaxf(acc[nf][i] + bv, 0.f);
                xout[(size_t)grow * D + col] = f2bf(v);
            }
        }
    }
}

// ---------------------------------------------------------------------------
// out[q] = fp32(x2b[x_nodes[q]]) + effect_emb[effect_ids[q]]
// ---------------------------------------------------------------------------
__global__ __launch_bounds__(256) void out_kernel(
    const ushort* __restrict__ x, const float* __restrict__ emb,
    const int* __restrict__ xn, const int* __restrict__ eid,
    float* __restrict__ out, int Q)
{
    long g = (long)blockIdx.x * 256 + threadIdx.x;
    long tot = (long)Q * 32;
    if (g >= tot) return;
    int q = (int)(g >> 5);
    int c = (int)(g & 31);
    int nq = xn[q], ef = eid[q];
    ushort4 xv = *((const ushort4*)(x + (size_t)nq * D) + c);
    float4  ev = *((const float4*)(emb + (size_t)ef * D) + c);
    float4 o = {bf2f(xv.x) + ev.x, bf2f(xv.y) + ev.y,
                bf2f(xv.z) + ev.z, bf2f(xv.w) + ev.w};
    ((float4*)out)[g] = o;
}

extern "C" void kernel_launch(void* const* d_in, const int* in_sizes, int n_in,
                              void* d_out, int out_size, void* d_ws, size_t ws_size,
                              hipStream_t stream)
{
    const float* graph_x   = (const float*)d_in[0];
    const int*   edge_idx  = (const int*)d_in[1];
    const int*   x_nodes   = (const int*)d_in[2];
    const int*   effect_id = (const int*)d_in[3];
    const float* chem      = (const float*)d_in[4];
    const float* W_self    = (const float*)d_in[5];
    const float* W_neigh   = (const float*)d_in[6];
    const float* bias      = (const float*)d_in[7];
    const float* eff_emb   = (const float*)d_in[8];

    const int N    = in_sizes[0] / D;
    const int E    = in_sizes[4];
    const int Q    = in_sizes[2];
    const int HOPS = in_sizes[7] / D;

    char* wsp = (char*)d_ws;
    int*    cnt     = (int*)wsp;     wsp += (size_t)N * 4;
    float*  denom   = (float*)wsp;   wsp += (size_t)N * 4;
    int*    pad_src = (int*)wsp;     wsp += (size_t)N * CAP * 4;
    float*  pad_w   = (float*)wsp;   wsp += (size_t)N * CAP * 4;
    ushort* xb      = (ushort*)wsp;  wsp += (size_t)N * D * 2;
    ushort* aggb    = (ushort*)wsp;  wsp += (size_t)N * D * 2;
    ushort* x1b     = (ushort*)wsp;  wsp += (size_t)N * D * 2;
    ushort* Wt      = (ushort*)wsp;  wsp += (size_t)HOPS * D * 256 * 2;

    hipMemsetAsync(cnt, 0, (size_t)N * 8, stream);

    const long n8 = (long)N * D / 8;
    convert_x<<<(int)((n8 + 255) / 256), 256, 0, stream>>>(graph_x, xb, n8);

    const int wtot = HOPS * D * 256;
    prep_wt<<<(wtot + 255) / 256, 256, 0, stream>>>(W_self, W_neigh, Wt, wtot);

    fill_edges<<<(E + 255) / 256, 256, 0, stream>>>(
        edge_idx, chem, cnt, denom, pad_src, pad_w, E);

    const int aggGrid  = (N + 3) / 4;
    const int gemmGrid = (N + BM - 1) / BM;

    for (int h = 0; h < HOPS; ++h) {
        const ushort* xin = (h == 0) ? xb : x1b;
        aggregate<<<aggGrid, 256, 0, stream>>>(
            xin, cnt, denom, pad_src, pad_w, aggb, N);
        gemm_mfma<<<gemmGrid, 256, 0, stream>>>(
            xin, aggb, Wt + (size_t)h * D * 256, bias + (size_t)h * D, x1b, N);
    }

    long tot = (long)Q * 32;
    out_kernel<<<(int)((tot + 255) / 256), 256, 0, stream>>>(
        x1b, eff_emb, x_nodes, effect_id, (float*)d_out, Q);
}

// Round 5
// 172.075 us; speedup vs baseline: 2.6698x; 1.0836x over previous
//
#include <hip/hip_runtime.h>
#include <hip/hip_bf16.h>

#define D 128
#define CAP 64   // max in-degree slots per node (Poisson(12); P(>=64) ~ 1e-24)
#define BM 64

using bf16x8 = __attribute__((ext_vector_type(8))) short;
using f32x4  = __attribute__((ext_vector_type(4))) float;

static __device__ __forceinline__ unsigned short f2bf(float f) {
    unsigned u = __float_as_uint(f);
    u += 0x7FFF + ((u >> 16) & 1);          // round-to-nearest-even
    return (unsigned short)(u >> 16);
}
static __device__ __forceinline__ float bf2f(unsigned short s) {
    return __uint_as_float(((unsigned)s) << 16);
}

// ---------------------------------------------------------------------------
// graph_x fp32 -> bf16 (8 elems / thread)
// ---------------------------------------------------------------------------
__global__ __launch_bounds__(256) void convert_x(
    const float* __restrict__ in, ushort* __restrict__ out, long n8)
{
    long i = (long)blockIdx.x * 256 + threadIdx.x;
    if (i >= n8) return;
    const float4* p = (const float4*)in + i * 2;
    float4 a = p[0], b = p[1];
    uint4 o;
    o.x = (unsigned)f2bf(a.x) | ((unsigned)f2bf(a.y) << 16);
    o.y = (unsigned)f2bf(a.z) | ((unsigned)f2bf(a.w) << 16);
    o.z = (unsigned)f2bf(b.x) | ((unsigned)f2bf(b.y) << 16);
    o.w = (unsigned)f2bf(b.z) | ((unsigned)f2bf(b.w) << 16);
    ((uint4*)out)[i] = o;
}

// ---------------------------------------------------------------------------
// Build Wt[h][n][k] (bf16): transposed stack of [W_self ; W_neigh] per hop.
// ---------------------------------------------------------------------------
__global__ __launch_bounds__(256) void prep_wt(
    const float* __restrict__ Ws, const float* __restrict__ Wn,
    ushort* __restrict__ Wt, int total)
{
    int idx = blockIdx.x * 256 + threadIdx.x;
    if (idx >= total) return;
    int h   = idx >> 15;          // /(D*256)
    int rem = idx & 32767;
    int n   = rem >> 8;
    int k   = rem & 255;
    float v = (k < D) ? Ws[(size_t)h * D * D + (size_t)k * D + n]
                      : Wn[(size_t)h * D * D + (size_t)(k - D) * D + n];
    Wt[idx] = f2bf(v);
}

// ---------------------------------------------------------------------------
// Padded adjacency: one returning atomic (slot) + one 8B scatter per edge.
// Weight is carried in the same int2 -> denom computed later in aggregate.
// ---------------------------------------------------------------------------
__global__ __launch_bounds__(256) void fill_edges(
    const int* __restrict__ ei, const float* __restrict__ w,
    int* __restrict__ cnt, int2* __restrict__ pad, int E)
{
    int e = blockIdx.x * 256 + threadIdx.x;
    if (e >= E) return;
    int s = ei[e];
    int d = ei[E + e];
    float wv = w[e];
    int pos = atomicAdd(&cnt[d], 1);
    if (pos < CAP) {
        pad[(size_t)d * CAP + pos] = make_int2(s, __float_as_int(wv));
    }
}

// ---------------------------------------------------------------------------
// Weighted-mean aggregation, bf16 features: one node per wave,
// lane = jj*32 + c (c = 4-col group, jj = j-slice), 8 gathers in flight.
// denom = sum of slot weights (computed inline, no separate array).
// Slots >= deg hold poison garbage -> predicate (s,w) to (0, 0.f).
// ---------------------------------------------------------------------------
__global__ __launch_bounds__(256) void aggregate(
    const ushort* __restrict__ x, const int* __restrict__ cnt,
    const int2* __restrict__ pad, ushort* __restrict__ agg, int N)
{
    const int wave = threadIdx.x >> 6;
    const int lane = threadIdx.x & 63;
    const int n = blockIdx.x * 4 + wave;
    if (n >= N) return;
    const int c  = lane & 31;
    const int jj = lane >> 5;

    int deg = cnt[n];
    if (deg > CAP) deg = CAP;
    const size_t base = (size_t)n * CAP;

    float ax = 0.f, ay = 0.f, az = 0.f, aw = 0.f, wsum = 0.f;

    for (int t = 0; t < deg; t += 8) {
        const int j = t + jj * 4;
        // 2 x 16B loads = 4 slots (addr (base+j)*8, j%4==0 -> 32B aligned)
        int4 p01 = *(const int4*)(pad + base + j);
        int4 p23 = *(const int4*)(pad + base + j + 2);
        const int s0 = (j + 0 < deg) ? p01.x : 0;
        const int s1 = (j + 1 < deg) ? p01.z : 0;
        const int s2 = (j + 2 < deg) ? p23.x : 0;
        const int s3 = (j + 3 < deg) ? p23.z : 0;
        const float w0 = (j + 0 < deg) ? __int_as_float(p01.y) : 0.f;
        const float w1 = (j + 1 < deg) ? __int_as_float(p01.w) : 0.f;
        const float w2 = (j + 2 < deg) ? __int_as_float(p23.y) : 0.f;
        const float w3 = (j + 3 < deg) ? __int_as_float(p23.w) : 0.f;
        ushort4 v0 = *((const ushort4*)(x + (size_t)s0 * D) + c);
        ushort4 v1 = *((const ushort4*)(x + (size_t)s1 * D) + c);
        ushort4 v2 = *((const ushort4*)(x + (size_t)s2 * D) + c);
        ushort4 v3 = *((const ushort4*)(x + (size_t)s3 * D) + c);
        ax += w0 * bf2f(v0.x) + w1 * bf2f(v1.x) + w2 * bf2f(v2.x) + w3 * bf2f(v3.x);
        ay += w0 * bf2f(v0.y) + w1 * bf2f(v1.y) + w2 * bf2f(v2.y) + w3 * bf2f(v3.y);
        az += w0 * bf2f(v0.z) + w1 * bf2f(v1.z) + w2 * bf2f(v2.z) + w3 * bf2f(v3.z);
        aw += w0 * bf2f(v0.w) + w1 * bf2f(v1.w) + w2 * bf2f(v2.w) + w3 * bf2f(v3.w);
        wsum += w0 + w1 + w2 + w3;
    }

    ax += __shfl_xor(ax, 32, 64);
    ay += __shfl_xor(ay, 32, 64);
    az += __shfl_xor(az, 32, 64);
    aw += __shfl_xor(aw, 32, 64);
    wsum += __shfl_xor(wsum, 32, 64);

    if (jj == 0) {
        const float inv = 1.f / fmaxf(wsum, 1e-12f);
        ushort4 o;
        o.x = f2bf(ax * inv); o.y = f2bf(ay * inv);
        o.z = f2bf(az * inv); o.w = f2bf(aw * inv);
        *((ushort4*)(agg + (size_t)n * D) + c) = o;
    }
}

// ---------------------------------------------------------------------------
// MFMA GEMM: xout = relu([xin|agg] @ Wt^T + bias), all bf16 I/O, fp32 acc.
// BM=64 rows/block, 4 waves (wave w = rows w*16..w*16+15), N=128 cols/wave,
// K=256 in 4 chunks of 64. LDS rows padded to 72 bf16.
// ---------------------------------------------------------------------------
__global__ __launch_bounds__(256) void gemm_mfma(
    const ushort* __restrict__ xin, const ushort* __restrict__ agg,
    const ushort* __restrict__ Wt, const float* __restrict__ bias,
    ushort* __restrict__ xout, int nrows)
{
    __shared__ ushort As[BM][72];
    __shared__ ushort Bs[D][72];
    const int tid  = threadIdx.x;
    const int w    = tid >> 6;
    const int lane = tid & 63;
    const int r16  = lane & 15;
    const int kq   = lane >> 4;
    const int row0 = blockIdx.x * BM;

    f32x4 acc[8];
    #pragma unroll
    for (int nf = 0; nf < 8; ++nf) acc[nf] = {0.f, 0.f, 0.f, 0.f};

    for (int kc = 0; kc < 4; ++kc) {
        // stage A chunk: 64 rows x 64 bf16 (4 threads/row x 16 ushorts)
        {
            const ushort* src = (kc < 2) ? xin : agg;
            const int kb = (kc & 1) * 64;
            const int r = tid >> 2, q = tid & 3;
            const int grow = row0 + r;
            if (grow < nrows) {
                const uint4* gp = (const uint4*)(src + (size_t)grow * D + kb + q * 16);
                uint4 v0 = gp[0], v1 = gp[1];
                *(uint4*)&As[r][q * 16]     = v0;
                *(uint4*)&As[r][q * 16 + 8] = v1;
            } else {
                uint4 z = {0u, 0u, 0u, 0u};
                *(uint4*)&As[r][q * 16]     = z;
                *(uint4*)&As[r][q * 16 + 8] = z;
            }
        }
        // stage B chunk: 128 rows x 64 bf16 (2 threads/row x 32 ushorts = 4 uint4)
        {
            const int n = tid >> 1, h2 = tid & 1;
            const uint4* gp = (const uint4*)(Wt + (size_t)n * 256 + kc * 64 + h2 * 32);
            uint4 v0 = gp[0], v1 = gp[1], v2 = gp[2], v3 = gp[3];
            *(uint4*)&Bs[n][h2 * 32]      = v0;
            *(uint4*)&Bs[n][h2 * 32 + 8]  = v1;
            *(uint4*)&Bs[n][h2 * 32 + 16] = v2;
            *(uint4*)&Bs[n][h2 * 32 + 24] = v3;
        }
        __syncthreads();
        #pragma unroll
        for (int kk = 0; kk < 64; kk += 32) {
            bf16x8 a = *(const bf16x8*)&As[w * 16 + r16][kk + kq * 8];
            #pragma unroll
            for (int nf = 0; nf < 8; ++nf) {
                bf16x8 b = *(const bf16x8*)&Bs[nf * 16 + r16][kk + kq * 8];
                acc[nf] = __builtin_amdgcn_mfma_f32_16x16x32_bf16(a, b, acc[nf], 0, 0, 0);
            }
        }
        __syncthreads();
    }
    // epilogue: bias + relu + bf16 store
    #pragma unroll
    for (int nf = 0; nf < 8; ++nf) {
        const int col = nf * 16 + r16;
        const float bv = bias[col];
        #pragma unroll
        for (int i = 0; i < 4; ++i) {
            const int grow = row0 + w * 16 + kq * 4 + i;
            if (grow < nrows) {
                float v = fmaxf(acc[nf][i] + bv, 0.f);
                xout[(size_t)grow * D + col] = f2bf(v);
            }
        }
    }
}

// ---------------------------------------------------------------------------
// out[q] = fp32(x2b[x_nodes[q]]) + effect_emb[effect_ids[q]]
// ---------------------------------------------------------------------------
__global__ __launch_bounds__(256) void out_kernel(
    const ushort* __restrict__ x, const float* __restrict__ emb,
    const int* __restrict__ xn, const int* __restrict__ eid,
    float* __restrict__ out, int Q)
{
    long g = (long)blockIdx.x * 256 + threadIdx.x;
    long tot = (long)Q * 32;
    if (g >= tot) return;
    int q = (int)(g >> 5);
    int c = (int)(g & 31);
    int nq = xn[q], ef = eid[q];
    ushort4 xv = *((const ushort4*)(x + (size_t)nq * D) + c);
    float4  ev = *((const float4*)(emb + (size_t)ef * D) + c);
    float4 o = {bf2f(xv.x) + ev.x, bf2f(xv.y) + ev.y,
                bf2f(xv.z) + ev.z, bf2f(xv.w) + ev.w};
    ((float4*)out)[g] = o;
}

extern "C" void kernel_launch(void* const* d_in, const int* in_sizes, int n_in,
                              void* d_out, int out_size, void* d_ws, size_t ws_size,
                              hipStream_t stream)
{
    const float* graph_x   = (const float*)d_in[0];
    const int*   edge_idx  = (const int*)d_in[1];
    const int*   x_nodes   = (const int*)d_in[2];
    const int*   effect_id = (const int*)d_in[3];
    const float* chem      = (const float*)d_in[4];
    const float* W_self    = (const float*)d_in[5];
    const float* W_neigh   = (const float*)d_in[6];
    const float* bias      = (const float*)d_in[7];
    const float* eff_emb   = (const float*)d_in[8];

    const int N    = in_sizes[0] / D;
    const int E    = in_sizes[4];
    const int Q    = in_sizes[2];
    const int HOPS = in_sizes[7] / D;

    char* wsp = (char*)d_ws;
    int*    cnt  = (int*)wsp;     wsp += (size_t)N * 4;
    int2*   pad  = (int2*)wsp;    wsp += (size_t)N * CAP * 8;
    ushort* xb   = (ushort*)wsp;  wsp += (size_t)N * D * 2;
    ushort* aggb = (ushort*)wsp;  wsp += (size_t)N * D * 2;
    ushort* x1b  = (ushort*)wsp;  wsp += (size_t)N * D * 2;
    ushort* Wt   = (ushort*)wsp;  wsp += (size_t)HOPS * D * 256 * 2;

    hipMemsetAsync(cnt, 0, (size_t)N * 4, stream);

    const long n8 = (long)N * D / 8;
    convert_x<<<(int)((n8 + 255) / 256), 256, 0, stream>>>(graph_x, xb, n8);

    const int wtot = HOPS * D * 256;
    prep_wt<<<(wtot + 255) / 256, 256, 0, stream>>>(W_self, W_neigh, Wt, wtot);

    fill_edges<<<(E + 255) / 256, 256, 0, stream>>>(
        edge_idx, chem, cnt, pad, E);

    const int aggGrid  = (N + 3) / 4;
    const int gemmGrid = (N + BM - 1) / BM;

    for (int h = 0; h < HOPS; ++h) {
        const ushort* xin = (h == 0) ? xb : x1b;
        aggregate<<<aggGrid, 256, 0, stream>>>(xin, cnt, pad, aggb, N);
        gemm_mfma<<<gemmGrid, 256, 0, stream>>>(
            xin, aggb, Wt + (size_t)h * D * 256, bias + (size_t)h * D, x1b, N);
    }

    long tot = (long)Q * 32;
    out_kernel<<<(int)((tot + 255) / 256), 256, 0, stream>>>(
        x1b, eff_emb, x_nodes, effect_id, (float*)d_out, Q);
}